// Round 3
// baseline (3105.654 us; speedup 1.0000x reference)
//
#include <hip/hip_runtime.h>
#include <math.h>

#define NN 50000
#define TT 9
#define FD 128
#define HD 128

using short8 = __attribute__((ext_vector_type(8))) short;
using f32x4  = __attribute__((ext_vector_type(4))) float;
typedef unsigned short ushort_t;

__device__ inline unsigned short f2bf(float x) {
  unsigned int u = __float_as_uint(x);
  unsigned int r = (u + 0x7fffu + ((u >> 16) & 1u)) >> 16;
  return (unsigned short)r;
}
__device__ inline float bf2f(unsigned short h) {
  return __uint_as_float(((unsigned int)h) << 16);
}
__device__ inline void split2(float x, unsigned short& h, unsigned short& l) {
  h = f2bf(x);
  l = f2bf(x - bf2f(h));
}
__device__ inline float fast_sigmoid(float x) {
  x = fminf(fmaxf(x, -30.f), 30.f);
  return 1.f / (1.f + __expf(-x));
}
__device__ inline float fast_tanh(float x) {
  x = fminf(fmaxf(x, -15.f), 15.f);
  float e = __expf(2.f * x);
  return (e - 1.f) / (e + 1.f);
}

// ---------------------------------------------------------------------------
// CSR build
// ---------------------------------------------------------------------------
__global__ void k_detect(const unsigned int* __restrict__ e32, int nchk,
                         int* __restrict__ stride_out) {
  __shared__ unsigned int red[256];
  unsigned int acc = 0;
  for (int i = threadIdx.x; i < nchk; i += 256) acc |= e32[2 * i + 1];
  red[threadIdx.x] = acc;
  __syncthreads();
  for (int s = 128; s > 0; s >>= 1) {
    if ((int)threadIdx.x < s) red[threadIdx.x] |= red[threadIdx.x + s];
    __syncthreads();
  }
  if (threadIdx.x == 0) stride_out[0] = (red[0] == 0u) ? 2 : 1;
}

__global__ void k_count(const unsigned int* __restrict__ e32, int E,
                        const int* __restrict__ stridep, int* __restrict__ cnt) {
  int e = blockIdx.x * 256 + threadIdx.x;
  if (e >= E) return;
  int st = stridep[0];
  int d = (int)e32[(size_t)(E + e) * st];
  atomicAdd(&cnt[d], 1);
}

__global__ void k_dinv(const int* __restrict__ cnt, float* __restrict__ dinv, int N) {
  int n = blockIdx.x * 256 + threadIdx.x;
  if (n < N) dinv[n] = rsqrtf((float)(cnt[n] + 1));
}

__global__ void k_scan(const int* __restrict__ cnt, int* __restrict__ rowp, int N) {
  __shared__ int buf[1024];
  __shared__ int carry_s;
  if (threadIdx.x == 0) carry_s = 0;
  __syncthreads();
  for (int base = 0; base < N; base += 1024) {
    int i = base + threadIdx.x;
    int v = (i < N) ? cnt[i] : 0;
    buf[threadIdx.x] = v;
    __syncthreads();
    for (int off = 1; off < 1024; off <<= 1) {
      int t = ((int)threadIdx.x >= off) ? buf[threadIdx.x - off] : 0;
      __syncthreads();
      buf[threadIdx.x] += t;
      __syncthreads();
    }
    int incl = buf[threadIdx.x];
    int carry = carry_s;
    if (i < N) rowp[i] = carry + incl - v;
    __syncthreads();
    if (threadIdx.x == 1023) carry_s = carry + incl;
    __syncthreads();
  }
  if (threadIdx.x == 0) rowp[N] = carry_s;
}

__global__ void k_scatter(const unsigned int* __restrict__ e32, int E,
                          const int* __restrict__ stridep, const int* __restrict__ rowp,
                          int* __restrict__ fill, int* __restrict__ col) {
  int e = blockIdx.x * 256 + threadIdx.x;
  if (e >= E) return;
  int st = stridep[0];
  int s = (int)e32[(size_t)e * st];
  int d = (int)e32[(size_t)(E + e) * st];
  int pos = rowp[d] + atomicAdd(&fill[d], 1);
  col[pos] = s;
}

// ---------------------------------------------------------------------------
// k_prep: xs[dc][t][n][16] = x_seq[t][n][dc*16+j] * dinv[n]   (fp32)
// ---------------------------------------------------------------------------
__global__ __launch_bounds__(256) void k_prep(const float* __restrict__ x,
                                              const float* __restrict__ dinv,
                                              float* __restrict__ xs) {
  int lane = threadIdx.x & 63;
  int n = blockIdx.x * 4 + (threadIdx.x >> 6);
  int t = blockIdx.y;
  float dn = dinv[n];
  float2 v = *(const float2*)(x + ((size_t)t * NN + n) * 128 + lane * 2);
  int dc = lane >> 3;
  int j = (2 * lane) & 15;
  float2 r;
  r.x = v.x * dn;
  r.y = v.y * dn;
  *(float2*)(xs + ((size_t)(dc * 9 + t) * NN + n) * 16 + j) = r;
}

// ---------------------------------------------------------------------------
// Weight packs: k-chunked [kchunk][row][8] so MFMA frag loads are coalesced.
// wpk: gate rows interleaved ri = jl*4+g; K=256 (emb | h)
// ---------------------------------------------------------------------------
__global__ void k_packw(const float* __restrict__ Wih, const float* __restrict__ Whh,
                        const float* __restrict__ bih, const float* __restrict__ bhh,
                        ushort_t* __restrict__ Wh_, ushort_t* __restrict__ Wl_,
                        float* __restrict__ bsum) {
  int r = blockIdx.x;   // 0..511 original gate-row
  int k = threadIdx.x;  // 0..255
  int ri = (r & 127) * 4 + (r >> 7);
  float v = (k < 128) ? Wih[(size_t)r * 128 + k] : Whh[(size_t)r * 128 + (k - 128)];
  unsigned short h, l;
  split2(v, h, l);
  size_t o = ((size_t)(k >> 3) * 512 + ri) * 8 + (k & 7);
  Wh_[o] = h;
  Wl_[o] = l;
  if (k == 0) bsum[ri] = bih[r] + bhh[r];
}

// wgt[kchunk][hid][8] = W_gcn[k][hid] split
__global__ void k_packg(const float* __restrict__ Wg, ushort_t* __restrict__ Bh_,
                        ushort_t* __restrict__ Bl_) {
  int h = blockIdx.x, k = threadIdx.x;  // 128 x 128
  unsigned short hh, ll;
  split2(Wg[(size_t)k * 128 + h], hh, ll);
  size_t o = ((size_t)(k >> 3) * 128 + h) * 8 + (k & 7);
  Bh_[o] = hh;
  Bl_[o] = ll;
}

// ---------------------------------------------------------------------------
// k_agg: wave = node; sweeps all 72 (dc,t) passes with 16-dim fp32 chunks so
// the gather working set (3.2MB) is per-XCD-L2 resident. x pre-scaled by dinv
// so no dinv gather. Output agg split-bf16, k-chunked [kchunk][t][n][8].
// ---------------------------------------------------------------------------
__global__ __launch_bounds__(256) void k_agg(const float* __restrict__ xs,
                                             const float* __restrict__ dinv,
                                             const int* __restrict__ rowp,
                                             const int* __restrict__ col,
                                             ushort_t* __restrict__ agg_h,
                                             ushort_t* __restrict__ agg_l) {
  int lane = threadIdx.x & 63;
  int n = blockIdx.x * 4 + (threadIdx.x >> 6);
  int slot = lane >> 3;        // edge slot 0..7
  int j2 = (lane & 7) * 2;     // dim pair within 16
  int beg = rowp[n], deg = rowp[n + 1] - beg;
  float dn = dinv[n];
  int ec = (lane < deg) ? col[beg + lane] : 0;
  bool multi = deg > 64;
#pragma unroll 1
  for (int dc = 0; dc < 8; ++dc) {
#pragma unroll 1
    for (int t = 0; t < 9; ++t) {
      const float* xb = xs + ((size_t)(dc * 9 + t) * NN) * 16;
      float ax = 0.f, ay = 0.f;
      if (slot == 0) {  // self-loop term (xs already holds dinv[n]*x[n])
        float2 sv = *(const float2*)(xb + (size_t)n * 16 + j2);
        ax = sv.x;
        ay = sv.y;
      }
      for (int base = 0; base < deg; base += 8) {
        if (multi && (base & 63) == 0) {
          ec = (base + lane < deg) ? col[beg + base + lane] : 0;
        }
        int src = __shfl(ec, (base & 63) + slot);
        if (base + slot < deg) {
          float2 v = *(const float2*)(xb + (size_t)src * 16 + j2);
          ax += v.x;
          ay += v.y;
        }
      }
#pragma unroll
      for (int m = 8; m <= 32; m <<= 1) {
        ax += __shfl_xor(ax, m);
        ay += __shfl_xor(ay, m);
      }
      ax *= dn;
      ay *= dn;
      if (slot == 0) {  // lanes 0..7 hold the 16 dims
        unsigned short hx, lx, hy, ly;
        split2(ax, hx, lx);
        split2(ay, hy, ly);
        int chunk = dc * 2 + (j2 >> 3);
        size_t ob = ((size_t)(chunk * 9 + t) * NN + n) * 8 + (j2 & 7);
        ushort2 vh, vl;
        vh.x = hx; vh.y = hy;
        vl.x = lx; vl.y = ly;
        *(ushort2*)(agg_h + ob) = vh;
        *(ushort2*)(agg_l + ob) = vl;
      }
    }
  }
}

// ---------------------------------------------------------------------------
// k_embm: emb = relu(agg @ W_gcn + b), batched over all t. Split-bf16 MFMA.
// grid (391, 9). All operand loads are k-chunked & coalesced.
// Output emb k-chunked [doct][t][n][8] hi/lo for the LSTM B-frags.
// ---------------------------------------------------------------------------
__global__ __launch_bounds__(256, 2) void k_embm(
    const ushort_t* __restrict__ Ah_, const ushort_t* __restrict__ Al_,
    const ushort_t* __restrict__ Bh_, const ushort_t* __restrict__ Bl_,
    const float* __restrict__ bg, ushort_t* __restrict__ Eh,
    ushort_t* __restrict__ El) {
  __shared__ unsigned int lds[128 * 133];
  int tid = threadIdx.x;
  int w = tid >> 6, lane = tid & 63, q = lane >> 4, cl = lane & 15;
  int t = blockIdx.y;
  int n0 = blockIdx.x * 128;
  const short8 zz = {0, 0, 0, 0, 0, 0, 0, 0};
  f32x4 acc[2][8] = {};
  for (int ks = 0; ks < 4; ++ks) {
    int chunk = ks * 4 + q;
    short8 bh[8], bl[8];
#pragma unroll
    for (int ct = 0; ct < 8; ++ct) {
      size_t o = ((size_t)chunk * 128 + ct * 16 + cl) * 8;
      bh[ct] = *(const short8*)(Bh_ + o);
      bl[ct] = *(const short8*)(Bl_ + o);
    }
#pragma unroll
    for (int rt = 0; rt < 2; ++rt) {
      int node = n0 + w * 32 + rt * 16 + cl;
      short8 ah = zz, al = zz;
      if (node < NN) {
        size_t o = ((size_t)(chunk * 9 + t) * NN + node) * 8;
        ah = *(const short8*)(Ah_ + o);
        al = *(const short8*)(Al_ + o);
      }
#pragma unroll
      for (int ct = 0; ct < 8; ++ct) {
        acc[rt][ct] = __builtin_amdgcn_mfma_f32_16x16x32_bf16(ah, bh[ct], acc[rt][ct], 0, 0, 0);
        acc[rt][ct] = __builtin_amdgcn_mfma_f32_16x16x32_bf16(ah, bl[ct], acc[rt][ct], 0, 0, 0);
        acc[rt][ct] = __builtin_amdgcn_mfma_f32_16x16x32_bf16(al, bh[ct], acc[rt][ct], 0, 0, 0);
      }
    }
  }
  // epilogue: bias+relu+split, pack (hi|lo) into LDS [node][hid]
#pragma unroll
  for (int rt = 0; rt < 2; ++rt) {
#pragma unroll
    for (int ct = 0; ct < 8; ++ct) {
      float bv = bg[ct * 16 + cl];
#pragma unroll
      for (int j = 0; j < 4; ++j) {
        int nl = w * 32 + rt * 16 + q * 4 + j;
        float v = acc[rt][ct][j] + bv;
        v = v > 0.f ? v : 0.f;
        unsigned short hh, hl;
        split2(v, hh, hl);
        lds[nl * 133 + ct * 16 + cl] = ((unsigned int)hh << 16) | hl;
      }
    }
  }
  __syncthreads();
  // writeback: thread -> (row, dim-oct); contiguous 16B stores
#pragma unroll
  for (int i = 0; i < 8; ++i) {
    int cid = i * 256 + tid;
    int row = cid & 127, doct = cid >> 7;
    int node = n0 + row;
    if (node >= NN) continue;
    union { unsigned int u[4]; short8 s; } rh, rl;
#pragma unroll
    for (int k2 = 0; k2 < 4; ++k2) {
      unsigned int v0 = lds[row * 133 + doct * 8 + k2 * 2];
      unsigned int v1 = lds[row * 133 + doct * 8 + k2 * 2 + 1];
      rh.u[k2] = __builtin_amdgcn_perm(v1, v0, 0x07060302u);
      rl.u[k2] = __builtin_amdgcn_perm(v1, v0, 0x05040100u);
    }
    size_t o = ((size_t)(doct * 9 + t) * NN + node) * 8;
    *(short8*)(Eh + o) = rh.s;
    *(short8*)(El + o) = rl.s;
  }
}

// ---------------------------------------------------------------------------
// k_lstm_all: the entire T=9 LSTM in ONE kernel. Block = 64 nodes, 4 waves.
// c lives in registers, h lives in LDS (packed bf16 hi|lo) across timesteps.
// gates^T[512 x 64] = Wpk[512x256] @ [emb|h]^T, split-bf16 (3 MFMA).
// Fused W_fc projection -> out[n][t].
// ---------------------------------------------------------------------------
__global__ __launch_bounds__(256, 2) void k_lstm_all(
    const ushort_t* __restrict__ Eh, const ushort_t* __restrict__ El,
    const ushort_t* __restrict__ Wh_, const ushort_t* __restrict__ Wl_,
    const float* __restrict__ bsum, const float* __restrict__ Wfc,
    const float* __restrict__ bfc, float* __restrict__ out) {
  __shared__ unsigned int ldsH[64 * 132];
  __shared__ float obuf[4][64];
  int tid = threadIdx.x;
  int w = tid >> 6, lane = tid & 63, q = lane >> 4, cl = lane & 15;
  int n0 = blockIdx.x * 64;
  const short8 zz = {0, 0, 0, 0, 0, 0, 0, 0};
  float cst[8][4] = {};
  float bfv = bfc[0];
#pragma unroll 1
  for (int t = 0; t < TT; ++t) {
    f32x4 acc[8][4] = {};
    int ksmax = (t == 0) ? 4 : 8;
#pragma unroll 1
    for (int ks = 0; ks < ksmax; ++ks) {
      short8 bh[4], bl[4];
      if (ks < 4) {  // emb part: global, k-chunked
        int chunk = ks * 4 + q;
        const ushort_t* ebh = Eh + ((size_t)(chunk * 9 + t) * NN) * 8;
        const ushort_t* ebl = El + ((size_t)(chunk * 9 + t) * NN) * 8;
#pragma unroll
        for (int ct = 0; ct < 4; ++ct) {
          int node = n0 + ct * 16 + cl;
          if (node < NN) {
            bh[ct] = *(const short8*)(ebh + (size_t)node * 8);
            bl[ct] = *(const short8*)(ebl + (size_t)node * 8);
          } else {
            bh[ct] = zz;
            bl[ct] = zz;
          }
        }
      } else {  // h part: LDS packed (hi|lo), unpack via v_perm
        int kk = (ks - 4) * 32 + q * 8;
#pragma unroll
        for (int ct = 0; ct < 4; ++ct) {
          int nl = ct * 16 + cl;
          const uint4* hp = (const uint4*)&ldsH[nl * 132 + kk];
          uint4 ua = hp[0], ub = hp[1];
          union { unsigned int u[4]; short8 s; } rh, rl;
          rh.u[0] = __builtin_amdgcn_perm(ua.y, ua.x, 0x07060302u);
          rh.u[1] = __builtin_amdgcn_perm(ua.w, ua.z, 0x07060302u);
          rh.u[2] = __builtin_amdgcn_perm(ub.y, ub.x, 0x07060302u);
          rh.u[3] = __builtin_amdgcn_perm(ub.w, ub.z, 0x07060302u);
          rl.u[0] = __builtin_amdgcn_perm(ua.y, ua.x, 0x05040100u);
          rl.u[1] = __builtin_amdgcn_perm(ua.w, ua.z, 0x05040100u);
          rl.u[2] = __builtin_amdgcn_perm(ub.y, ub.x, 0x05040100u);
          rl.u[3] = __builtin_amdgcn_perm(ub.w, ub.z, 0x05040100u);
          bh[ct] = rh.s;
          bl[ct] = rl.s;
        }
      }
      int chunk = ks * 4 + q;  // K=256 chunk index into wpk
#pragma unroll
      for (int rt = 0; rt < 8; ++rt) {
        int row = w * 128 + rt * 16 + cl;
        size_t ao = ((size_t)chunk * 512 + row) * 8;
        short8 ah = *(const short8*)(Wh_ + ao);
        short8 al = *(const short8*)(Wl_ + ao);
#pragma unroll
        for (int ct = 0; ct < 4; ++ct) {
          acc[rt][ct] = __builtin_amdgcn_mfma_f32_16x16x32_bf16(ah, bh[ct], acc[rt][ct], 0, 0, 0);
          acc[rt][ct] = __builtin_amdgcn_mfma_f32_16x16x32_bf16(ah, bl[ct], acc[rt][ct], 0, 0, 0);
          acc[rt][ct] = __builtin_amdgcn_mfma_f32_16x16x32_bf16(al, bh[ct], acc[rt][ct], 0, 0, 0);
        }
      }
    }
    __syncthreads();  // all ldsH(t-1) reads done
    float op[4] = {0.f, 0.f, 0.f, 0.f};
#pragma unroll
    for (int rt = 0; rt < 8; ++rt) {
      int jl = w * 32 + rt * 4 + q;
      float4 bs = *(const float4*)(bsum + jl * 4);
      float wf = Wfc[jl];
#pragma unroll
      for (int ct = 0; ct < 4; ++ct) {
        float gi = acc[rt][ct][0] + bs.x;
        float gf = acc[rt][ct][1] + bs.y;
        float gg = acc[rt][ct][2] + bs.z;
        float go = acc[rt][ct][3] + bs.w;
        float ig = fast_sigmoid(gi), fg = fast_sigmoid(gf), og = fast_sigmoid(go);
        float gt = fast_tanh(gg);
        float cn = fg * cst[rt][ct] + ig * gt;
        cst[rt][ct] = cn;
        float hn = og * fast_tanh(cn);
        op[ct] += hn * wf;
        unsigned short hh, hl;
        split2(hn, hh, hl);
        ldsH[(ct * 16 + cl) * 132 + jl] = ((unsigned int)hh << 16) | hl;
      }
    }
#pragma unroll
    for (int ct = 0; ct < 4; ++ct) {
      op[ct] += __shfl_xor(op[ct], 16);
      op[ct] += __shfl_xor(op[ct], 32);
    }
    if (q == 0) {
#pragma unroll
      for (int ct = 0; ct < 4; ++ct) obuf[w][ct * 16 + cl] = op[ct];
    }
    __syncthreads();  // h(t) + obuf visible
    if (tid < 64) {
      int node = n0 + tid;
      if (node < NN) {
        out[(size_t)node * TT + t] =
            obuf[0][tid] + obuf[1][tid] + obuf[2][tid] + obuf[3][tid] + bfv;
      }
    }
  }
}

// ---------------------------------------------------------------------------
static inline size_t alignup(size_t x) { return (x + 511) & ~(size_t)511; }

extern "C" void kernel_launch(void* const* d_in, const int* in_sizes, int n_in,
                              void* d_out, int out_size, void* d_ws, size_t ws_size,
                              hipStream_t stream) {
  const float* x_seq = (const float*)d_in[0];
  const unsigned int* e32 = (const unsigned int*)d_in[1];
  const float* W_gcn = (const float*)d_in[2];
  const float* b_gcn = (const float*)d_in[3];
  const float* W_ih = (const float*)d_in[4];
  const float* W_hh = (const float*)d_in[5];
  const float* b_ih = (const float*)d_in[6];
  const float* b_hh = (const float*)d_in[7];
  const float* W_fc = (const float*)d_in[8];
  const float* b_fc = (const float*)d_in[9];
  float* out = (float*)d_out;

  const int N = NN;
  const int E = in_sizes[1] / 2;

  char* p = (char*)d_ws;
  int* stridep = (int*)p;                    p += 512;
  int* cnt = (int*)p;                        p += alignup((size_t)N * 4);
  int* rowp = (int*)p;                       p += alignup((size_t)(N + 1) * 4);
  int* col = (int*)p;                        p += alignup((size_t)E * 4);
  float* dinv = (float*)p;                   p += alignup((size_t)N * 4);
  float* xs = (float*)p;                     p += alignup((size_t)8 * 9 * N * 16 * 4);
  ushort_t* agg_h = (ushort_t*)p;            p += alignup((size_t)16 * 9 * N * 8 * 2);
  ushort_t* agg_l = (ushort_t*)p;            p += alignup((size_t)16 * 9 * N * 8 * 2);
  ushort_t* emb_h = (ushort_t*)p;            p += alignup((size_t)16 * 9 * N * 8 * 2);
  ushort_t* emb_l = (ushort_t*)p;            p += alignup((size_t)16 * 9 * N * 8 * 2);
  ushort_t* wpkh = (ushort_t*)p;             p += alignup((size_t)32 * 512 * 8 * 2);
  ushort_t* wpkl = (ushort_t*)p;             p += alignup((size_t)32 * 512 * 8 * 2);
  ushort_t* wgth = (ushort_t*)p;             p += alignup((size_t)16 * 128 * 8 * 2);
  ushort_t* wgtl = (ushort_t*)p;             p += alignup((size_t)16 * 128 * 8 * 2);
  float* bsum = (float*)p;                   p += alignup((size_t)512 * 4);

  hipMemsetAsync(cnt, 0, (size_t)N * 4, stream);

  int nchk = E < 8192 ? E : 8192;
  k_detect<<<1, 256, 0, stream>>>(e32, nchk, stridep);
  k_count<<<(E + 255) / 256, 256, 0, stream>>>(e32, E, stridep, cnt);
  k_dinv<<<(N + 255) / 256, 256, 0, stream>>>(cnt, dinv, N);
  k_scan<<<1, 1024, 0, stream>>>(cnt, rowp, N);
  hipMemsetAsync(cnt, 0, (size_t)N * 4, stream);  // reuse as fill
  k_scatter<<<(E + 255) / 256, 256, 0, stream>>>(e32, E, stridep, rowp, cnt, col);
  k_prep<<<dim3(N / 4, 9), 256, 0, stream>>>(x_seq, dinv, xs);
  k_packw<<<512, 256, 0, stream>>>(W_ih, W_hh, b_ih, b_hh, wpkh, wpkl, bsum);
  k_packg<<<128, 128, 0, stream>>>(W_gcn, wgth, wgtl);

  k_agg<<<N / 4, 256, 0, stream>>>(xs, dinv, rowp, col, agg_h, agg_l);
  k_embm<<<dim3((N + 127) / 128, 9), 256, 0, stream>>>(agg_h, agg_l, wgth, wgtl,
                                                       b_gcn, emb_h, emb_l);
  k_lstm_all<<<(N + 63) / 64, 256, 0, stream>>>(emb_h, emb_l, wpkh, wpkl, bsum,
                                                W_fc, b_fc, out);
}

// Round 4
// 1855.803 us; speedup vs baseline: 1.6735x; 1.6735x over previous
//
#include <hip/hip_runtime.h>
#include <math.h>

#define NN 50000
#define TT 9
#define FD 128
#define HD 128

using short8 = __attribute__((ext_vector_type(8))) short;
using f32x4  = __attribute__((ext_vector_type(4))) float;
using half2v = __attribute__((ext_vector_type(2))) _Float16;
typedef unsigned short ushort_t;

__device__ inline unsigned short f2bf(float x) {
  unsigned int u = __float_as_uint(x);
  unsigned int r = (u + 0x7fffu + ((u >> 16) & 1u)) >> 16;
  return (unsigned short)r;
}
__device__ inline float bf2f(unsigned short h) {
  return __uint_as_float(((unsigned int)h) << 16);
}
__device__ inline void split2(float x, unsigned short& h, unsigned short& l) {
  h = f2bf(x);
  l = f2bf(x - bf2f(h));
}
__device__ inline float fast_sigmoid(float x) {
  x = fminf(fmaxf(x, -30.f), 30.f);
  return 1.f / (1.f + __expf(-x));
}
__device__ inline float fast_tanh(float x) {
  x = fminf(fmaxf(x, -15.f), 15.f);
  float e = __expf(2.f * x);
  return (e - 1.f) / (e + 1.f);
}

// ---------------------------------------------------------------------------
// CSR build
// ---------------------------------------------------------------------------
__global__ void k_detect(const unsigned int* __restrict__ e32, int nchk,
                         int* __restrict__ stride_out) {
  __shared__ unsigned int red[256];
  unsigned int acc = 0;
  for (int i = threadIdx.x; i < nchk; i += 256) acc |= e32[2 * i + 1];
  red[threadIdx.x] = acc;
  __syncthreads();
  for (int s = 128; s > 0; s >>= 1) {
    if ((int)threadIdx.x < s) red[threadIdx.x] |= red[threadIdx.x + s];
    __syncthreads();
  }
  if (threadIdx.x == 0) stride_out[0] = (red[0] == 0u) ? 2 : 1;
}

__global__ void k_count(const unsigned int* __restrict__ e32, int E,
                        const int* __restrict__ stridep, int* __restrict__ cnt) {
  int e = blockIdx.x * 256 + threadIdx.x;
  if (e >= E) return;
  int st = stridep[0];
  int d = (int)e32[(size_t)(E + e) * st];
  atomicAdd(&cnt[d], 1);
}

__global__ void k_dinv(const int* __restrict__ cnt, float* __restrict__ dinv, int N) {
  int n = blockIdx.x * 256 + threadIdx.x;
  if (n < N) dinv[n] = rsqrtf((float)(cnt[n] + 1));
}

__global__ void k_scan(const int* __restrict__ cnt, int* __restrict__ rowp, int N) {
  __shared__ int buf[1024];
  __shared__ int carry_s;
  if (threadIdx.x == 0) carry_s = 0;
  __syncthreads();
  for (int base = 0; base < N; base += 1024) {
    int i = base + threadIdx.x;
    int v = (i < N) ? cnt[i] : 0;
    buf[threadIdx.x] = v;
    __syncthreads();
    for (int off = 1; off < 1024; off <<= 1) {
      int t = ((int)threadIdx.x >= off) ? buf[threadIdx.x - off] : 0;
      __syncthreads();
      buf[threadIdx.x] += t;
      __syncthreads();
    }
    int incl = buf[threadIdx.x];
    int carry = carry_s;
    if (i < N) rowp[i] = carry + incl - v;
    __syncthreads();
    if (threadIdx.x == 1023) carry_s = carry + incl;
    __syncthreads();
  }
  if (threadIdx.x == 0) rowp[N] = carry_s;
}

__global__ void k_scatter(const unsigned int* __restrict__ e32, int E,
                          const int* __restrict__ stridep, const int* __restrict__ rowp,
                          int* __restrict__ fill, int* __restrict__ col) {
  int e = blockIdx.x * 256 + threadIdx.x;
  if (e >= E) return;
  int st = stridep[0];
  int s = (int)e32[(size_t)e * st];
  int d = (int)e32[(size_t)(E + e) * st];
  int pos = rowp[d] + atomicAdd(&fill[d], 1);
  col[pos] = s;
}

// ---------------------------------------------------------------------------
// k_prep: xs16[t][n][128] = fp16( x_seq[t][n][d] * dinv[n] )
// ---------------------------------------------------------------------------
__global__ __launch_bounds__(256) void k_prep(const float* __restrict__ x,
                                              const float* __restrict__ dinv,
                                              _Float16* __restrict__ xs) {
  int lane = threadIdx.x & 63;
  int n = blockIdx.x * 4 + (threadIdx.x >> 6);
  int t = blockIdx.y;
  float dn = dinv[n];
  float2 v = *(const float2*)(x + ((size_t)t * NN + n) * 128 + lane * 2);
  half2v r;
  r.x = (_Float16)(v.x * dn);
  r.y = (_Float16)(v.y * dn);
  *(half2v*)(xs + ((size_t)t * NN + n) * 128 + lane * 2) = r;
}

// ---------------------------------------------------------------------------
// Weight packs: k-chunked [kchunk][row][8] so MFMA frag loads are coalesced.
// ---------------------------------------------------------------------------
__global__ void k_packw(const float* __restrict__ Wih, const float* __restrict__ Whh,
                        const float* __restrict__ bih, const float* __restrict__ bhh,
                        ushort_t* __restrict__ Wh_, ushort_t* __restrict__ Wl_,
                        float* __restrict__ bsum) {
  int r = blockIdx.x;   // 0..511 original gate-row
  int k = threadIdx.x;  // 0..255
  int ri = (r & 127) * 4 + (r >> 7);
  float v = (k < 128) ? Wih[(size_t)r * 128 + k] : Whh[(size_t)r * 128 + (k - 128)];
  unsigned short h, l;
  split2(v, h, l);
  size_t o = ((size_t)(k >> 3) * 512 + ri) * 8 + (k & 7);
  Wh_[o] = h;
  Wl_[o] = l;
  if (k == 0) bsum[ri] = bih[r] + bhh[r];
}

__global__ void k_packg(const float* __restrict__ Wg, ushort_t* __restrict__ Bh_,
                        ushort_t* __restrict__ Bl_) {
  int h = blockIdx.x, k = threadIdx.x;  // 128 x 128
  unsigned short hh, ll;
  split2(Wg[(size_t)k * 128 + h], hh, ll);
  size_t o = ((size_t)(k >> 3) * 128 + h) * 8 + (k & 7);
  Bh_[o] = hh;
  Bl_[o] = ll;
}

// ---------------------------------------------------------------------------
// k_agg (per-t launch, L3-resident 25.6MB working set): wave = node, full
// 128-dim fp16 row gather (256B/edge, coalesced). fp32 accumulate, split-bf16
// output in k-chunked layout via LDS-staged 64B-contiguous writeback.
// ---------------------------------------------------------------------------
__global__ __launch_bounds__(256) void k_agg(const _Float16* __restrict__ xs,
                                             const float* __restrict__ dinv,
                                             const int* __restrict__ rowp,
                                             const int* __restrict__ col,
                                             ushort_t* __restrict__ agg_h,
                                             ushort_t* __restrict__ agg_l, int t) {
  __shared__ unsigned int pk[4][128];
  int lane = threadIdx.x & 63;
  int wv = threadIdx.x >> 6;
  int n = blockIdx.x * 4 + wv;
  const _Float16* xb = xs + (size_t)t * NN * 128;
  float dn = dinv[n];
  half2v sv = *(const half2v*)(xb + (size_t)n * 128 + lane * 2);
  float ax = (float)sv.x, ay = (float)sv.y;  // self-loop (xs pre-scaled by dinv)
  int beg = rowp[n], end = rowp[n + 1];
  for (int base = beg; base < end; base += 64) {
    int m = end - base;
    if (m > 64) m = 64;
    int sl = (lane < m) ? col[base + lane] : 0;
    for (int j = 0; j < m; ++j) {
      int s = __shfl(sl, j);
      half2v g = *(const half2v*)(xb + (size_t)s * 128 + lane * 2);
      ax += (float)g.x;
      ay += (float)g.y;
    }
  }
  unsigned short hx, lx, hy, ly;
  split2(ax * dn, hx, lx);
  split2(ay * dn, hy, ly);
  pk[wv][lane * 2] = ((unsigned int)hx << 16) | lx;
  pk[wv][lane * 2 + 1] = ((unsigned int)hy << 16) | ly;
  __syncthreads();
  // writeback: tid -> (chunk 0..15, node g 0..3, elem-pair e2)
  int tid = threadIdx.x;
  int chunk = tid >> 4, g = (tid >> 2) & 3, e2 = (tid & 3) * 2;
  unsigned int p0 = pk[g][chunk * 8 + e2];
  unsigned int p1 = pk[g][chunk * 8 + e2 + 1];
  int n2 = blockIdx.x * 4 + g;
  size_t ob = ((size_t)(chunk * 9 + t) * NN + n2) * 8 + e2;
  ushort2 vh, vl;
  vh.x = (unsigned short)(p0 >> 16);
  vh.y = (unsigned short)(p1 >> 16);
  vl.x = (unsigned short)(p0 & 0xffffu);
  vl.y = (unsigned short)(p1 & 0xffffu);
  *(ushort2*)(agg_h + ob) = vh;
  *(ushort2*)(agg_l + ob) = vl;
}

// ---------------------------------------------------------------------------
// k_embm: emb = relu(agg @ W_gcn + b), batched over all t. Split-bf16 MFMA.
// ---------------------------------------------------------------------------
__global__ __launch_bounds__(256, 2) void k_embm(
    const ushort_t* __restrict__ Ah_, const ushort_t* __restrict__ Al_,
    const ushort_t* __restrict__ Bh_, const ushort_t* __restrict__ Bl_,
    const float* __restrict__ bg, ushort_t* __restrict__ Eh,
    ushort_t* __restrict__ El) {
  __shared__ unsigned int lds[128 * 133];
  int tid = threadIdx.x;
  int w = tid >> 6, lane = tid & 63, q = lane >> 4, cl = lane & 15;
  int t = blockIdx.y;
  int n0 = blockIdx.x * 128;
  const short8 zz = {0, 0, 0, 0, 0, 0, 0, 0};
  f32x4 acc[2][8] = {};
  for (int ks = 0; ks < 4; ++ks) {
    int chunk = ks * 4 + q;
    short8 bh[8], bl[8];
#pragma unroll
    for (int ct = 0; ct < 8; ++ct) {
      size_t o = ((size_t)chunk * 128 + ct * 16 + cl) * 8;
      bh[ct] = *(const short8*)(Bh_ + o);
      bl[ct] = *(const short8*)(Bl_ + o);
    }
#pragma unroll
    for (int rt = 0; rt < 2; ++rt) {
      int node = n0 + w * 32 + rt * 16 + cl;
      short8 ah = zz, al = zz;
      if (node < NN) {
        size_t o = ((size_t)(chunk * 9 + t) * NN + node) * 8;
        ah = *(const short8*)(Ah_ + o);
        al = *(const short8*)(Al_ + o);
      }
#pragma unroll
      for (int ct = 0; ct < 8; ++ct) {
        acc[rt][ct] = __builtin_amdgcn_mfma_f32_16x16x32_bf16(ah, bh[ct], acc[rt][ct], 0, 0, 0);
        acc[rt][ct] = __builtin_amdgcn_mfma_f32_16x16x32_bf16(ah, bl[ct], acc[rt][ct], 0, 0, 0);
        acc[rt][ct] = __builtin_amdgcn_mfma_f32_16x16x32_bf16(al, bh[ct], acc[rt][ct], 0, 0, 0);
      }
    }
  }
  // epilogue: bias+relu+split, pack (hi|lo) into LDS [node][hid]
#pragma unroll
  for (int rt = 0; rt < 2; ++rt) {
#pragma unroll
    for (int ct = 0; ct < 8; ++ct) {
      float bv = bg[ct * 16 + cl];
#pragma unroll
      for (int j = 0; j < 4; ++j) {
        int nl = w * 32 + rt * 16 + q * 4 + j;
        float v = acc[rt][ct][j] + bv;
        v = v > 0.f ? v : 0.f;
        unsigned short hh, hl;
        split2(v, hh, hl);
        lds[nl * 133 + ct * 16 + cl] = ((unsigned int)hh << 16) | hl;
      }
    }
  }
  __syncthreads();
#pragma unroll
  for (int i = 0; i < 8; ++i) {
    int cid = i * 256 + tid;
    int row = cid & 127, doct = cid >> 7;
    int node = n0 + row;
    if (node >= NN) continue;
    union { unsigned int u[4]; short8 s; } rh, rl;
#pragma unroll
    for (int k2 = 0; k2 < 4; ++k2) {
      unsigned int v0 = lds[row * 133 + doct * 8 + k2 * 2];
      unsigned int v1 = lds[row * 133 + doct * 8 + k2 * 2 + 1];
      rh.u[k2] = __builtin_amdgcn_perm(v1, v0, 0x07060302u);
      rl.u[k2] = __builtin_amdgcn_perm(v1, v0, 0x05040100u);
    }
    size_t o = ((size_t)(doct * 9 + t) * NN + node) * 8;
    *(short8*)(Eh + o) = rh.s;
    *(short8*)(El + o) = rl.s;
  }
}

// ---------------------------------------------------------------------------
// k_lstm_all: entire T=9 LSTM in one kernel. Block = 64 nodes, 4 waves.
// c in registers, h in LDS (bf16 hi|lo packed) across timesteps.
// ---------------------------------------------------------------------------
__global__ __launch_bounds__(256, 2) void k_lstm_all(
    const ushort_t* __restrict__ Eh, const ushort_t* __restrict__ El,
    const ushort_t* __restrict__ Wh_, const ushort_t* __restrict__ Wl_,
    const float* __restrict__ bsum, const float* __restrict__ Wfc,
    const float* __restrict__ bfc, float* __restrict__ out) {
  __shared__ unsigned int ldsH[64 * 132];
  __shared__ float obuf[4][64];
  int tid = threadIdx.x;
  int w = tid >> 6, lane = tid & 63, q = lane >> 4, cl = lane & 15;
  int n0 = blockIdx.x * 64;
  const short8 zz = {0, 0, 0, 0, 0, 0, 0, 0};
  float cst[8][4] = {};
  float bfv = bfc[0];
#pragma unroll 1
  for (int t = 0; t < TT; ++t) {
    f32x4 acc[8][4] = {};
    int ksmax = (t == 0) ? 4 : 8;
#pragma unroll 1
    for (int ks = 0; ks < ksmax; ++ks) {
      short8 bh[4], bl[4];
      if (ks < 4) {  // emb part: global, k-chunked
        int chunk = ks * 4 + q;
        const ushort_t* ebh = Eh + ((size_t)(chunk * 9 + t) * NN) * 8;
        const ushort_t* ebl = El + ((size_t)(chunk * 9 + t) * NN) * 8;
#pragma unroll
        for (int ct = 0; ct < 4; ++ct) {
          int node = n0 + ct * 16 + cl;
          if (node < NN) {
            bh[ct] = *(const short8*)(ebh + (size_t)node * 8);
            bl[ct] = *(const short8*)(ebl + (size_t)node * 8);
          } else {
            bh[ct] = zz;
            bl[ct] = zz;
          }
        }
      } else {  // h part: LDS packed (hi|lo), unpack via v_perm
        int kk = (ks - 4) * 32 + q * 8;
#pragma unroll
        for (int ct = 0; ct < 4; ++ct) {
          int nl = ct * 16 + cl;
          const uint4* hp = (const uint4*)&ldsH[nl * 132 + kk];
          uint4 ua = hp[0], ub = hp[1];
          union { unsigned int u[4]; short8 s; } rh, rl;
          rh.u[0] = __builtin_amdgcn_perm(ua.y, ua.x, 0x07060302u);
          rh.u[1] = __builtin_amdgcn_perm(ua.w, ua.z, 0x07060302u);
          rh.u[2] = __builtin_amdgcn_perm(ub.y, ub.x, 0x07060302u);
          rh.u[3] = __builtin_amdgcn_perm(ub.w, ub.z, 0x07060302u);
          rl.u[0] = __builtin_amdgcn_perm(ua.y, ua.x, 0x05040100u);
          rl.u[1] = __builtin_amdgcn_perm(ua.w, ua.z, 0x05040100u);
          rl.u[2] = __builtin_amdgcn_perm(ub.y, ub.x, 0x05040100u);
          rl.u[3] = __builtin_amdgcn_perm(ub.w, ub.z, 0x05040100u);
          bh[ct] = rh.s;
          bl[ct] = rl.s;
        }
      }
      int chunk = ks * 4 + q;  // K=256 chunk index into wpk
#pragma unroll
      for (int rt = 0; rt < 8; ++rt) {
        int row = w * 128 + rt * 16 + cl;
        size_t ao = ((size_t)chunk * 512 + row) * 8;
        short8 ah = *(const short8*)(Wh_ + ao);
        short8 al = *(const short8*)(Wl_ + ao);
#pragma unroll
        for (int ct = 0; ct < 4; ++ct) {
          acc[rt][ct] = __builtin_amdgcn_mfma_f32_16x16x32_bf16(ah, bh[ct], acc[rt][ct], 0, 0, 0);
          acc[rt][ct] = __builtin_amdgcn_mfma_f32_16x16x32_bf16(ah, bl[ct], acc[rt][ct], 0, 0, 0);
          acc[rt][ct] = __builtin_amdgcn_mfma_f32_16x16x32_bf16(al, bh[ct], acc[rt][ct], 0, 0, 0);
        }
      }
    }
    __syncthreads();  // all ldsH(t-1) reads done
    float op[4] = {0.f, 0.f, 0.f, 0.f};
#pragma unroll
    for (int rt = 0; rt < 8; ++rt) {
      int jl = w * 32 + rt * 4 + q;
      float4 bs = *(const float4*)(bsum + jl * 4);
      float wf = Wfc[jl];
#pragma unroll
      for (int ct = 0; ct < 4; ++ct) {
        float gi = acc[rt][ct][0] + bs.x;
        float gf = acc[rt][ct][1] + bs.y;
        float gg = acc[rt][ct][2] + bs.z;
        float go = acc[rt][ct][3] + bs.w;
        float ig = fast_sigmoid(gi), fg = fast_sigmoid(gf), og = fast_sigmoid(go);
        float gt = fast_tanh(gg);
        float cn = fg * cst[rt][ct] + ig * gt;
        cst[rt][ct] = cn;
        float hn = og * fast_tanh(cn);
        op[ct] += hn * wf;
        unsigned short hh, hl;
        split2(hn, hh, hl);
        ldsH[(ct * 16 + cl) * 132 + jl] = ((unsigned int)hh << 16) | hl;
      }
    }
#pragma unroll
    for (int ct = 0; ct < 4; ++ct) {
      op[ct] += __shfl_xor(op[ct], 16);
      op[ct] += __shfl_xor(op[ct], 32);
    }
    if (q == 0) {
#pragma unroll
      for (int ct = 0; ct < 4; ++ct) obuf[w][ct * 16 + cl] = op[ct];
    }
    __syncthreads();  // h(t) + obuf visible
    if (tid < 64) {
      int node = n0 + tid;
      if (node < NN) {
        out[(size_t)node * TT + t] =
            obuf[0][tid] + obuf[1][tid] + obuf[2][tid] + obuf[3][tid] + bfv;
      }
    }
  }
}

// ---------------------------------------------------------------------------
static inline size_t alignup(size_t x) { return (x + 511) & ~(size_t)511; }

extern "C" void kernel_launch(void* const* d_in, const int* in_sizes, int n_in,
                              void* d_out, int out_size, void* d_ws, size_t ws_size,
                              hipStream_t stream) {
  const float* x_seq = (const float*)d_in[0];
  const unsigned int* e32 = (const unsigned int*)d_in[1];
  const float* W_gcn = (const float*)d_in[2];
  const float* b_gcn = (const float*)d_in[3];
  const float* W_ih = (const float*)d_in[4];
  const float* W_hh = (const float*)d_in[5];
  const float* b_ih = (const float*)d_in[6];
  const float* b_hh = (const float*)d_in[7];
  const float* W_fc = (const float*)d_in[8];
  const float* b_fc = (const float*)d_in[9];
  float* out = (float*)d_out;

  const int N = NN;
  const int E = in_sizes[1] / 2;

  char* p = (char*)d_ws;
  int* stridep = (int*)p;                    p += 512;
  int* cnt = (int*)p;                        p += alignup((size_t)N * 4);
  int* rowp = (int*)p;                       p += alignup((size_t)(N + 1) * 4);
  int* col = (int*)p;                        p += alignup((size_t)E * 4);
  float* dinv = (float*)p;                   p += alignup((size_t)N * 4);
  _Float16* xs16 = (_Float16*)p;             p += alignup((size_t)9 * N * 128 * 2);
  ushort_t* agg_h = (ushort_t*)p;            p += alignup((size_t)16 * 9 * N * 8 * 2);
  ushort_t* agg_l = (ushort_t*)p;            p += alignup((size_t)16 * 9 * N * 8 * 2);
  ushort_t* emb_h = (ushort_t*)p;            p += alignup((size_t)16 * 9 * N * 8 * 2);
  ushort_t* emb_l = (ushort_t*)p;            p += alignup((size_t)16 * 9 * N * 8 * 2);
  ushort_t* wpkh = (ushort_t*)p;             p += alignup((size_t)32 * 512 * 8 * 2);
  ushort_t* wpkl = (ushort_t*)p;             p += alignup((size_t)32 * 512 * 8 * 2);
  ushort_t* wgth = (ushort_t*)p;             p += alignup((size_t)16 * 128 * 8 * 2);
  ushort_t* wgtl = (ushort_t*)p;             p += alignup((size_t)16 * 128 * 8 * 2);
  float* bsum = (float*)p;                   p += alignup((size_t)512 * 4);

  hipMemsetAsync(cnt, 0, (size_t)N * 4, stream);

  int nchk = E < 8192 ? E : 8192;
  k_detect<<<1, 256, 0, stream>>>(e32, nchk, stridep);
  k_count<<<(E + 255) / 256, 256, 0, stream>>>(e32, E, stridep, cnt);
  k_dinv<<<(N + 255) / 256, 256, 0, stream>>>(cnt, dinv, N);
  k_scan<<<1, 1024, 0, stream>>>(cnt, rowp, N);
  hipMemsetAsync(cnt, 0, (size_t)N * 4, stream);  // reuse as fill
  k_scatter<<<(E + 255) / 256, 256, 0, stream>>>(e32, E, stridep, rowp, cnt, col);
  k_prep<<<dim3(N / 4, 9), 256, 0, stream>>>(x_seq, dinv, xs16);
  k_packw<<<512, 256, 0, stream>>>(W_ih, W_hh, b_ih, b_hh, wpkh, wpkl, bsum);
  k_packg<<<128, 128, 0, stream>>>(W_gcn, wgth, wgtl);

  for (int t = 0; t < TT; ++t) {
    k_agg<<<N / 4, 256, 0, stream>>>(xs16, dinv, rowp, col, agg_h, agg_l, t);
  }
  k_embm<<<dim3((N + 127) / 128, 9), 256, 0, stream>>>(agg_h, agg_l, wgth, wgtl,
                                                       b_gcn, emb_h, emb_l);
  k_lstm_all<<<(N + 63) / 64, 256, 0, stream>>>(emb_h, emb_l, wpkh, wpkl, bsum,
                                                W_fc, b_fc, out);
}

// Round 5
// 1442.449 us; speedup vs baseline: 2.1530x; 1.2866x over previous
//
#include <hip/hip_runtime.h>
#include <math.h>

#define NN 50000
#define TT 9
#define FD 128
#define HD 128

using short8 = __attribute__((ext_vector_type(8))) short;
using f32x4  = __attribute__((ext_vector_type(4))) float;
using half2v = __attribute__((ext_vector_type(2))) _Float16;
typedef unsigned short ushort_t;

__device__ inline unsigned short f2bf(float x) {
  unsigned int u = __float_as_uint(x);
  unsigned int r = (u + 0x7fffu + ((u >> 16) & 1u)) >> 16;
  return (unsigned short)r;
}
__device__ inline float bf2f(unsigned short h) {
  return __uint_as_float(((unsigned int)h) << 16);
}
__device__ inline void split2(float x, unsigned short& h, unsigned short& l) {
  h = f2bf(x);
  l = f2bf(x - bf2f(h));
}
__device__ inline float fast_sigmoid(float x) {
  x = fminf(fmaxf(x, -30.f), 30.f);
  return 1.f / (1.f + __expf(-x));
}
__device__ inline float fast_tanh(float x) {
  x = fminf(fmaxf(x, -15.f), 15.f);
  float e = __expf(2.f * x);
  return (e - 1.f) / (e + 1.f);
}

// ---------------------------------------------------------------------------
// CSR build
// ---------------------------------------------------------------------------
__global__ void k_detect(const unsigned int* __restrict__ e32, int nchk,
                         int* __restrict__ stride_out) {
  __shared__ unsigned int red[256];
  unsigned int acc = 0;
  for (int i = threadIdx.x; i < nchk; i += 256) acc |= e32[2 * i + 1];
  red[threadIdx.x] = acc;
  __syncthreads();
  for (int s = 128; s > 0; s >>= 1) {
    if ((int)threadIdx.x < s) red[threadIdx.x] |= red[threadIdx.x + s];
    __syncthreads();
  }
  if (threadIdx.x == 0) stride_out[0] = (red[0] == 0u) ? 2 : 1;
}

__global__ void k_count(const unsigned int* __restrict__ e32, int E,
                        const int* __restrict__ stridep, int* __restrict__ cnt) {
  int e = blockIdx.x * 256 + threadIdx.x;
  if (e >= E) return;
  int st = stridep[0];
  int d = (int)e32[(size_t)(E + e) * st];
  atomicAdd(&cnt[d], 1);
}

__global__ void k_dinv(const int* __restrict__ cnt, float* __restrict__ dinv, int N) {
  int n = blockIdx.x * 256 + threadIdx.x;
  if (n < N) dinv[n] = rsqrtf((float)(cnt[n] + 1));
}

__global__ void k_scan(const int* __restrict__ cnt, int* __restrict__ rowp, int N) {
  __shared__ int buf[1024];
  __shared__ int carry_s;
  if (threadIdx.x == 0) carry_s = 0;
  __syncthreads();
  for (int base = 0; base < N; base += 1024) {
    int i = base + threadIdx.x;
    int v = (i < N) ? cnt[i] : 0;
    buf[threadIdx.x] = v;
    __syncthreads();
    for (int off = 1; off < 1024; off <<= 1) {
      int t = ((int)threadIdx.x >= off) ? buf[threadIdx.x - off] : 0;
      __syncthreads();
      buf[threadIdx.x] += t;
      __syncthreads();
    }
    int incl = buf[threadIdx.x];
    int carry = carry_s;
    if (i < N) rowp[i] = carry + incl - v;
    __syncthreads();
    if (threadIdx.x == 1023) carry_s = carry + incl;
    __syncthreads();
  }
  if (threadIdx.x == 0) rowp[N] = carry_s;
}

__global__ void k_scatter(const unsigned int* __restrict__ e32, int E,
                          const int* __restrict__ stridep, const int* __restrict__ rowp,
                          int* __restrict__ fill, int* __restrict__ col) {
  int e = blockIdx.x * 256 + threadIdx.x;
  if (e >= E) return;
  int st = stridep[0];
  int s = (int)e32[(size_t)e * st];
  int d = (int)e32[(size_t)(E + e) * st];
  int pos = rowp[d] + atomicAdd(&fill[d], 1);
  col[pos] = s;
}

// ---------------------------------------------------------------------------
// k_prep: xs16[t][n][128] = fp16( x_seq[t][n][d] * dinv[n] )
// ---------------------------------------------------------------------------
__global__ __launch_bounds__(256) void k_prep(const float* __restrict__ x,
                                              const float* __restrict__ dinv,
                                              _Float16* __restrict__ xs) {
  int lane = threadIdx.x & 63;
  int n = blockIdx.x * 4 + (threadIdx.x >> 6);
  int t = blockIdx.y;
  float dn = dinv[n];
  float2 v = *(const float2*)(x + ((size_t)t * NN + n) * 128 + lane * 2);
  half2v r;
  r.x = (_Float16)(v.x * dn);
  r.y = (_Float16)(v.y * dn);
  *(half2v*)(xs + ((size_t)t * NN + n) * 128 + lane * 2) = r;
}

// ---------------------------------------------------------------------------
// Weight packs: k-chunked [kchunk][row][8] so MFMA frag loads are coalesced.
// ---------------------------------------------------------------------------
__global__ void k_packw(const float* __restrict__ Wih, const float* __restrict__ Whh,
                        const float* __restrict__ bih, const float* __restrict__ bhh,
                        ushort_t* __restrict__ Wh_, ushort_t* __restrict__ Wl_,
                        float* __restrict__ bsum) {
  int r = blockIdx.x;   // 0..511 original gate-row
  int k = threadIdx.x;  // 0..255
  int ri = (r & 127) * 4 + (r >> 7);
  float v = (k < 128) ? Wih[(size_t)r * 128 + k] : Whh[(size_t)r * 128 + (k - 128)];
  unsigned short h, l;
  split2(v, h, l);
  size_t o = ((size_t)(k >> 3) * 512 + ri) * 8 + (k & 7);
  Wh_[o] = h;
  Wl_[o] = l;
  if (k == 0) bsum[ri] = bih[r] + bhh[r];
}

__global__ void k_packg(const float* __restrict__ Wg, ushort_t* __restrict__ Bh_,
                        ushort_t* __restrict__ Bl_) {
  int h = blockIdx.x, k = threadIdx.x;  // 128 x 128
  unsigned short hh, ll;
  split2(Wg[(size_t)k * 128 + h], hh, ll);
  size_t o = ((size_t)(k >> 3) * 128 + h) * 8 + (k & 7);
  Bh_[o] = hh;
  Bl_[o] = ll;
}

// ---------------------------------------------------------------------------
// k_agg: grid (N/4, 9); wave = node, full 128-dim fp16 row gather, unroll-8
// for MLP. fp32 accumulate, split-bf16 k-chunked output via LDS-staged pack.
// ---------------------------------------------------------------------------
__global__ __launch_bounds__(256) void k_agg(const _Float16* __restrict__ xs,
                                             const float* __restrict__ dinv,
                                             const int* __restrict__ rowp,
                                             const int* __restrict__ col,
                                             ushort_t* __restrict__ agg_h,
                                             ushort_t* __restrict__ agg_l) {
  __shared__ unsigned int pk[4][128];
  int lane = threadIdx.x & 63;
  int wv = threadIdx.x >> 6;
  int n = blockIdx.x * 4 + wv;
  int t = blockIdx.y;
  const _Float16* xb = xs + (size_t)t * NN * 128;
  float dn = dinv[n];
  half2v sv = *(const half2v*)(xb + (size_t)n * 128 + lane * 2);
  float ax = (float)sv.x, ay = (float)sv.y;  // self-loop (xs pre-scaled by dinv)
  int beg = rowp[n], end = rowp[n + 1];
  for (int base = beg; base < end; base += 64) {
    int m = end - base;
    if (m > 64) m = 64;
    int sl = (lane < m) ? col[base + lane] : 0;
    int j = 0;
    for (; j + 8 <= m; j += 8) {
      int s[8];
#pragma unroll
      for (int u = 0; u < 8; ++u) s[u] = __shfl(sl, j + u);
      half2v g[8];
#pragma unroll
      for (int u = 0; u < 8; ++u)
        g[u] = *(const half2v*)(xb + (size_t)s[u] * 128 + lane * 2);
#pragma unroll
      for (int u = 0; u < 8; ++u) {
        ax += (float)g[u].x;
        ay += (float)g[u].y;
      }
    }
    for (; j < m; ++j) {
      int s = __shfl(sl, j);
      half2v g = *(const half2v*)(xb + (size_t)s * 128 + lane * 2);
      ax += (float)g.x;
      ay += (float)g.y;
    }
  }
  unsigned short hx, lx, hy, ly;
  split2(ax * dn, hx, lx);
  split2(ay * dn, hy, ly);
  pk[wv][lane * 2] = ((unsigned int)hx << 16) | lx;
  pk[wv][lane * 2 + 1] = ((unsigned int)hy << 16) | ly;
  __syncthreads();
  // writeback: tid -> (chunk 0..15, node g 0..3, elem-pair e2)
  int tid = threadIdx.x;
  int chunk = tid >> 4, g = (tid >> 2) & 3, e2 = (tid & 3) * 2;
  unsigned int p0 = pk[g][chunk * 8 + e2];
  unsigned int p1 = pk[g][chunk * 8 + e2 + 1];
  int n2 = blockIdx.x * 4 + g;
  size_t ob = ((size_t)(chunk * 9 + t) * NN + n2) * 8 + e2;
  ushort2 vh, vl;
  vh.x = (unsigned short)(p0 >> 16);
  vh.y = (unsigned short)(p1 >> 16);
  vl.x = (unsigned short)(p0 & 0xffffu);
  vl.y = (unsigned short)(p1 & 0xffffu);
  *(ushort2*)(agg_h + ob) = vh;
  *(ushort2*)(agg_l + ob) = vl;
}

// ---------------------------------------------------------------------------
// k_fused: GCN GEMM + full T=9 LSTM + out-projection in one kernel.
// Block: 512 threads (8 waves) x 48 nodes. Per t:
//  Phase E: emb^T[128hid x 48n] = Wgt[128x128k] @ agg^T  (split-bf16, 3 MFMA)
//           -> relu+bias -> split -> ldsE (transposed, hi|lo packed)
//  Phase G: gates^T[512 x 48n] = Wpk[512x256k] @ [emb|h]^T  (B from ldsE/ldsH)
//           -> sigmoid/tanh epilogue, c in regs, h -> ldsH, fused W_fc -> out
// rt=4 x ct=3 -> acc 48 VGPR; target VGPR<=128 for 2 blocks/CU (16 waves).
// ---------------------------------------------------------------------------
#define BN 48
__global__ __launch_bounds__(512, 4) void k_fused(
    const ushort_t* __restrict__ Ah_, const ushort_t* __restrict__ Al_,
    const ushort_t* __restrict__ Gh_, const ushort_t* __restrict__ Gl_,
    const float* __restrict__ bg, const ushort_t* __restrict__ Wh_,
    const ushort_t* __restrict__ Wl_, const float* __restrict__ bsum,
    const float* __restrict__ Wfc, const float* __restrict__ bfc,
    float* __restrict__ out) {
  __shared__ unsigned int ldsE[BN * 132];
  __shared__ unsigned int ldsH[BN * 132];
  __shared__ float obuf[8][BN];
  int tid = threadIdx.x;
  int w = tid >> 6, lane = tid & 63, q = lane >> 4, cl = lane & 15;
  int n0 = blockIdx.x * BN;
  const short8 zz = {0, 0, 0, 0, 0, 0, 0, 0};
  float cst[4][3] = {};
  float bfv = bfc[0];
#pragma unroll 1
  for (int t = 0; t < TT; ++t) {
    // ---- Phase E: emb GEMM (rows = hid, cols = nodes) ----
    {
      f32x4 acce[3] = {};
#pragma unroll 1
      for (int ks = 0; ks < 4; ++ks) {
        int chunk = ks * 4 + q;
        size_t ao = ((size_t)chunk * 128 + w * 16 + cl) * 8;
        short8 gah = *(const short8*)(Gh_ + ao);
        short8 gal = *(const short8*)(Gl_ + ao);
#pragma unroll
        for (int ct = 0; ct < 3; ++ct) {
          int node = n0 + ct * 16 + cl;
          short8 bh = zz, bl = zz;
          if (node < NN) {
            size_t o = ((size_t)(chunk * 9 + t) * NN + node) * 8;
            bh = *(const short8*)(Ah_ + o);
            bl = *(const short8*)(Al_ + o);
          }
          acce[ct] = __builtin_amdgcn_mfma_f32_16x16x32_bf16(gah, bh, acce[ct], 0, 0, 0);
          acce[ct] = __builtin_amdgcn_mfma_f32_16x16x32_bf16(gah, bl, acce[ct], 0, 0, 0);
          acce[ct] = __builtin_amdgcn_mfma_f32_16x16x32_bf16(gal, bh, acce[ct], 0, 0, 0);
        }
      }
#pragma unroll
      for (int ct = 0; ct < 3; ++ct) {
#pragma unroll
        for (int j = 0; j < 4; ++j) {
          int hid = w * 16 + q * 4 + j;
          float v = acce[ct][j] + bg[hid];
          v = v > 0.f ? v : 0.f;
          unsigned short hh, hl;
          split2(v, hh, hl);
          ldsE[(ct * 16 + cl) * 132 + hid] = ((unsigned int)hh << 16) | hl;
        }
      }
    }
    __syncthreads();  // BAR1: ldsE(t) ready; ldsH(t-1) writes already fenced
    // ---- Phase G: gates GEMM ----
    f32x4 acc[4][3] = {};
    int ksmax = (t == 0) ? 4 : 8;
#pragma unroll 1
    for (int ks = 0; ks < ksmax; ++ks) {
      int chunk = ks * 4 + q;
      const unsigned int* ldsB = (ks < 4) ? ldsE : ldsH;
      int kk = (ks & 3) * 32 + q * 8;
      short8 bh[3], bl[3];
#pragma unroll
      for (int ct = 0; ct < 3; ++ct) {
        const uint4* hp = (const uint4*)&ldsB[(ct * 16 + cl) * 132 + kk];
        uint4 ua = hp[0], ub = hp[1];
        union { unsigned int u[4]; short8 s; } rh, rl;
        rh.u[0] = __builtin_amdgcn_perm(ua.y, ua.x, 0x07060302u);
        rh.u[1] = __builtin_amdgcn_perm(ua.w, ua.z, 0x07060302u);
        rh.u[2] = __builtin_amdgcn_perm(ub.y, ub.x, 0x07060302u);
        rh.u[3] = __builtin_amdgcn_perm(ub.w, ub.z, 0x07060302u);
        rl.u[0] = __builtin_amdgcn_perm(ua.y, ua.x, 0x05040100u);
        rl.u[1] = __builtin_amdgcn_perm(ua.w, ua.z, 0x05040100u);
        rl.u[2] = __builtin_amdgcn_perm(ub.y, ub.x, 0x05040100u);
        rl.u[3] = __builtin_amdgcn_perm(ub.w, ub.z, 0x05040100u);
        bh[ct] = rh.s;
        bl[ct] = rl.s;
      }
#pragma unroll
      for (int rt = 0; rt < 4; ++rt) {
        size_t ao = ((size_t)chunk * 512 + w * 64 + rt * 16 + cl) * 8;
        short8 ah = *(const short8*)(Wh_ + ao);
        short8 al = *(const short8*)(Wl_ + ao);
#pragma unroll
        for (int ct = 0; ct < 3; ++ct) {
          acc[rt][ct] = __builtin_amdgcn_mfma_f32_16x16x32_bf16(ah, bh[ct], acc[rt][ct], 0, 0, 0);
          acc[rt][ct] = __builtin_amdgcn_mfma_f32_16x16x32_bf16(ah, bl[ct], acc[rt][ct], 0, 0, 0);
          acc[rt][ct] = __builtin_amdgcn_mfma_f32_16x16x32_bf16(al, bh[ct], acc[rt][ct], 0, 0, 0);
        }
      }
    }
    __syncthreads();  // BAR2: all ldsE/ldsH reads done before h(t) writes
    // ---- Epilogue: gates -> c,h ; h -> ldsH ; fused W_fc ----
    float op[3] = {0.f, 0.f, 0.f};
#pragma unroll
    for (int rt = 0; rt < 4; ++rt) {
      int jl = w * 16 + rt * 4 + q;
      float4 bs = *(const float4*)(bsum + jl * 4);
      float wf = Wfc[jl];
#pragma unroll
      for (int ct = 0; ct < 3; ++ct) {
        float gi = acc[rt][ct][0] + bs.x;
        float gf = acc[rt][ct][1] + bs.y;
        float gg = acc[rt][ct][2] + bs.z;
        float go = acc[rt][ct][3] + bs.w;
        float ig = fast_sigmoid(gi), fg = fast_sigmoid(gf), og = fast_sigmoid(go);
        float gt = fast_tanh(gg);
        float cn = fg * cst[rt][ct] + ig * gt;
        cst[rt][ct] = cn;
        float hn = og * fast_tanh(cn);
        op[ct] += hn * wf;
        unsigned short hh, hl;
        split2(hn, hh, hl);
        ldsH[(ct * 16 + cl) * 132 + jl] = ((unsigned int)hh << 16) | hl;
      }
    }
#pragma unroll
    for (int ct = 0; ct < 3; ++ct) {
      op[ct] += __shfl_xor(op[ct], 16);
      op[ct] += __shfl_xor(op[ct], 32);
    }
    if (q == 0) {
#pragma unroll
      for (int ct = 0; ct < 3; ++ct) obuf[w][ct * 16 + cl] = op[ct];
    }
    __syncthreads();  // BAR3: h(t) + obuf visible
    if (tid < BN) {
      int node = n0 + tid;
      if (node < NN) {
        float v = bfv;
#pragma unroll
        for (int ww = 0; ww < 8; ++ww) v += obuf[ww][tid];
        out[(size_t)node * TT + t] = v;
      }
    }
  }
}

// ---------------------------------------------------------------------------
static inline size_t alignup(size_t x) { return (x + 511) & ~(size_t)511; }

extern "C" void kernel_launch(void* const* d_in, const int* in_sizes, int n_in,
                              void* d_out, int out_size, void* d_ws, size_t ws_size,
                              hipStream_t stream) {
  const float* x_seq = (const float*)d_in[0];
  const unsigned int* e32 = (const unsigned int*)d_in[1];
  const float* W_gcn = (const float*)d_in[2];
  const float* b_gcn = (const float*)d_in[3];
  const float* W_ih = (const float*)d_in[4];
  const float* W_hh = (const float*)d_in[5];
  const float* b_ih = (const float*)d_in[6];
  const float* b_hh = (const float*)d_in[7];
  const float* W_fc = (const float*)d_in[8];
  const float* b_fc = (const float*)d_in[9];
  float* out = (float*)d_out;

  const int N = NN;
  const int E = in_sizes[1] / 2;

  char* p = (char*)d_ws;
  int* stridep = (int*)p;                    p += 512;
  int* cnt = (int*)p;                        p += alignup((size_t)N * 4);
  int* rowp = (int*)p;                       p += alignup((size_t)(N + 1) * 4);
  int* col = (int*)p;                        p += alignup((size_t)E * 4);
  float* dinv = (float*)p;                   p += alignup((size_t)N * 4);
  _Float16* xs16 = (_Float16*)p;             p += alignup((size_t)9 * N * 128 * 2);
  ushort_t* agg_h = (ushort_t*)p;            p += alignup((size_t)16 * 9 * N * 8 * 2);
  ushort_t* agg_l = (ushort_t*)p;            p += alignup((size_t)16 * 9 * N * 8 * 2);
  ushort_t* wpkh = (ushort_t*)p;             p += alignup((size_t)32 * 512 * 8 * 2);
  ushort_t* wpkl = (ushort_t*)p;             p += alignup((size_t)32 * 512 * 8 * 2);
  ushort_t* wgth = (ushort_t*)p;             p += alignup((size_t)16 * 128 * 8 * 2);
  ushort_t* wgtl = (ushort_t*)p;             p += alignup((size_t)16 * 128 * 8 * 2);
  float* bsum = (float*)p;                   p += alignup((size_t)512 * 4);

  hipMemsetAsync(cnt, 0, (size_t)N * 4, stream);

  int nchk = E < 8192 ? E : 8192;
  k_detect<<<1, 256, 0, stream>>>(e32, nchk, stridep);
  k_count<<<(E + 255) / 256, 256, 0, stream>>>(e32, E, stridep, cnt);
  k_dinv<<<(N + 255) / 256, 256, 0, stream>>>(cnt, dinv, N);
  k_scan<<<1, 1024, 0, stream>>>(cnt, rowp, N);
  hipMemsetAsync(cnt, 0, (size_t)N * 4, stream);  // reuse as fill
  k_scatter<<<(E + 255) / 256, 256, 0, stream>>>(e32, E, stridep, rowp, cnt, col);
  k_prep<<<dim3(N / 4, 9), 256, 0, stream>>>(x_seq, dinv, xs16);
  k_packw<<<512, 256, 0, stream>>>(W_ih, W_hh, b_ih, b_hh, wpkh, wpkl, bsum);
  k_packg<<<128, 128, 0, stream>>>(W_gcn, wgth, wgtl);

  k_agg<<<dim3(N / 4, 9), 256, 0, stream>>>(xs16, dinv, rowp, col, agg_h, agg_l);
  k_fused<<<(N + BN - 1) / BN, 512, 0, stream>>>(agg_h, agg_l, wgth, wgtl, b_gcn,
                                                 wpkh, wpkl, bsum, W_fc, b_fc, out);
}